// Round 10
// baseline (531.472 us; speedup 1.0000x reference)
//
#include <hip/hip_runtime.h>

#define T_LEN 512

typedef _Float16 h2_t  __attribute__((ext_vector_type(2)));
typedef _Float16 f16x8 __attribute__((ext_vector_type(8)));
typedef float    f32x4 __attribute__((ext_vector_type(4)));

__device__ __forceinline__ float sigf(float x) {
    return 1.0f / (1.0f + __expf(-x));
}
__device__ __forceinline__ float tanhf_(float x) {
    return 2.0f / (1.0f + __expf(-2.0f * x)) - 1.0f;
}
__device__ __forceinline__ unsigned pack2(float x, float y) {
    h2_t p; p[0] = (_Float16)x; p[1] = (_Float16)y;
    return __builtin_bit_cast(unsigned, p);
}

// DPP quad-perm pair swap (lane 2k <-> 2k+1), VALU speed.
__device__ __forceinline__ float dpp_xor1(float x) {
    int i = __builtin_bit_cast(int, x);
    i = __builtin_amdgcn_mov_dpp(i, 0xB1, 0xF, 0xF, true);
    return __builtin_bit_cast(float, i);
}

#if defined(__has_builtin)
#  if __has_builtin(__builtin_amdgcn_fdot2)
#    define FDOT2(a, b, c) __builtin_amdgcn_fdot2((a), (b), (c), false)
#  endif
#endif
#ifndef FDOT2
__device__ __forceinline__ float fdot2_fb(h2_t a, h2_t b, float c) {
    return fmaf((float)a[0], (float)b[0], fmaf((float)a[1], (float)b[1], c));
}
#  define FDOT2(a, b, c) fdot2_fb((a), (b), (c))
#endif

// Raw barrier: waits LDS ops only (lgkmcnt), leaves global loads in flight.
// For 1-wave workgroups s_barrier is free -> this is just a same-wave LDS fence.
__device__ __forceinline__ void lds_barrier() {
    asm volatile("s_waitcnt lgkmcnt(0)" ::: "memory");
    __builtin_amdgcn_s_barrier();
    asm volatile("" ::: "memory");
}

// ---------------- Prep: Wt1[col 0..511][k 0..319] f16 (x-part, col>=256 -> w1b) --
__global__ __launch_bounds__(64) void prep_w1(
    const float* __restrict__ w1f, const float* __restrict__ w1b,
    _Float16* __restrict__ Wt1)
{
    const int col = blockIdx.x;
    const int t   = threadIdx.x;
    if (t >= 40) return;
    const float* __restrict__ W = (col < 256) ? w1f : w1b;
    const int c = col & 255;
    f16x8 v;
    #pragma unroll
    for (int i = 0; i < 8; ++i) {
        int k = t * 8 + i;
        float x = (k < 300) ? W[(size_t)k * 256 + c] : 0.0f;
        v[i] = (_Float16)x;
    }
    *(f16x8*)(Wt1 + (size_t)col * 320 + t * 8) = v;
}

// ---------------- Prep: Wt2[col 0..255][k 0..127] f16 (x-part, col>=128 -> w2b) --
__global__ __launch_bounds__(64) void prep_w2(
    const float* __restrict__ w2f, const float* __restrict__ w2b,
    _Float16* __restrict__ Wt2)
{
    const int col = blockIdx.x;
    const int t   = threadIdx.x;
    if (t >= 16) return;
    const float* __restrict__ W = (col < 128) ? w2f : w2b;
    const int c = col & 127;
    f16x8 v;
    #pragma unroll
    for (int i = 0; i < 8; ++i) {
        int k = t * 8 + i;
        v[i] = (_Float16)W[(size_t)k * 128 + c];
    }
    *(f16x8*)(Wt2 + (size_t)col * 128 + t * 8) = v;
}

// ---------------- Prep: Whr1[dir*256 + colp][k 0..63] f16, colp = u*4+g ----------
__global__ __launch_bounds__(64) void prep_whr1(
    const float* __restrict__ w1f, const float* __restrict__ w1b,
    _Float16* __restrict__ Whr1)
{
    const int x    = blockIdx.x;          // 0..511
    const int dir  = x >> 8, colp = x & 255;
    const int u = colp >> 2, g = colp & 3;
    const int k = threadIdx.x;            // 0..63
    const float* __restrict__ W = dir ? w1b : w1f;
    Whr1[(size_t)x * 64 + k] = (_Float16)W[(size_t)(300 + k) * 256 + g * 64 + u];
}

// ---------------- Prep: Whr2[dir*128 + colp][k 0..31] f16, colp = u*4+g ----------
__global__ __launch_bounds__(64) void prep_whr2(
    const float* __restrict__ w2f, const float* __restrict__ w2b,
    _Float16* __restrict__ Whr2)
{
    const int x    = blockIdx.x;          // 0..255
    const int dir  = x >> 7, colp = x & 127;
    const int u = colp >> 2, g = colp & 3;
    const int k = threadIdx.x;
    if (k >= 32) return;
    const float* __restrict__ W = dir ? w2b : w2f;
    Whr2[(size_t)x * 32 + k] = (_Float16)W[(size_t)(128 + k) * 128 + g * 32 + u];
}

// ---------------- GEMM1 (MFMA f16): Z1p = gather(emb,tok) @ Wx1 + b1 ----------
// Z1p layout: [dir*64+b][t][colp = u*4+g] f32 (one float4 per unit per step).
__global__ __launch_bounds__(256, 1) void gemm1_kernel(
    const int* __restrict__ tok, const float* __restrict__ emb,
    const _Float16* __restrict__ Wt1,
    const float* __restrict__ b1f, const float* __restrict__ b1b,
    float* __restrict__ Z1p)
{
    const int row0 = blockIdx.x * 64;            // flat row = b*512 + t
    const int b    = row0 >> 9;
    const int t0   = row0 & 511;
    const int tid  = threadIdx.x;

    __shared__ __align__(16) _Float16 A_lds[64][328];

    {
        const int row = tid >> 2, q = tid & 3;
        const int tk = tok[b * T_LEN + t0 + row];
        const float* __restrict__ src = emb + (size_t)tk * 300 + q * 80;
        #pragma unroll
        for (int i = 0; i < 20; ++i) {
            float4 v;
            if (q == 3 && i >= 15) v = make_float4(0.f, 0.f, 0.f, 0.f);
            else                   v = *(const float4*)(src + i * 4);
            uint2 u; u.x = pack2(v.x, v.y); u.y = pack2(v.z, v.w);
            *(uint2*)&A_lds[row][q * 80 + i * 4] = u;
        }
    }
    __syncthreads();

    const int l   = tid & 63;
    const int w   = tid >> 6;
    const int wN0 = w * 128;
    const int lr  = l & 15;
    const int lk8 = (l >> 4) * 8;

    f32x4 acc[4][8] = {};

    #pragma unroll 2
    for (int ks = 0; ks < 10; ++ks) {
        const int k0 = ks * 32;
        f16x8 af[4];
        #pragma unroll
        for (int m = 0; m < 4; ++m)
            af[m] = *(const f16x8*)&A_lds[m * 16 + lr][k0 + lk8];
        f16x8 bf[8];
        #pragma unroll
        for (int n = 0; n < 8; ++n)
            bf[n] = *(const f16x8*)(Wt1 + (size_t)(wN0 + n * 16 + lr) * 320 + k0 + lk8);
        #pragma unroll
        for (int m = 0; m < 4; ++m)
            #pragma unroll
            for (int n = 0; n < 8; ++n)
                acc[m][n] = __builtin_amdgcn_mfma_f32_16x16x32_f16(af[m], bf[n], acc[m][n], 0, 0, 0);
    }

    const int dir = wN0 >> 8;
    const int rq  = (l >> 4) * 4;
    #pragma unroll
    for (int n = 0; n < 8; ++n) {
        const int colr = (wN0 + n * 16 + lr) & 255;
        const int colp = (colr & 63) * 4 + (colr >> 6);
        const float bv = dir ? b1b[colr] : b1f[colr];
        #pragma unroll
        for (int m = 0; m < 4; ++m) {
            const size_t rb = (size_t)dir * 32768 + row0 + m * 16 + rq;
            #pragma unroll
            for (int r = 0; r < 4; ++r)
                Z1p[(rb + r) * 256 + colp] = acc[m][n][r] + bv;
        }
    }
}

// ---------------- GEMM2 (MFMA f16): Z2p = H1f @ Wx2 + b2 ----------------
// H1f: [b][t][128] f16. Z2p: [dir*64+b][t][colp = u*4+g] f32.
__global__ __launch_bounds__(256, 1) void gemm2_kernel(
    const _Float16* __restrict__ H1f,
    const _Float16* __restrict__ Wt2,
    const float* __restrict__ b2f, const float* __restrict__ b2b,
    float* __restrict__ Z2p)
{
    const int row0 = blockIdx.x * 64;
    const int tid  = threadIdx.x;

    __shared__ __align__(16) _Float16 A_lds[64][136];

    {
        const int row = tid >> 2, q = tid & 3;
        const _Float16* __restrict__ src = H1f + (size_t)(row0 + row) * 128 + q * 32;
        #pragma unroll
        for (int i = 0; i < 4; ++i)
            *(f16x8*)&A_lds[row][q * 32 + i * 8] = *(const f16x8*)(src + i * 8);
    }
    __syncthreads();

    const int l   = tid & 63;
    const int w   = tid >> 6;
    const int wN0 = w * 64;
    const int lr  = l & 15;
    const int lk8 = (l >> 4) * 8;

    f32x4 acc[4][4] = {};

    #pragma unroll
    for (int ks = 0; ks < 4; ++ks) {
        const int k0 = ks * 32;
        f16x8 af[4];
        #pragma unroll
        for (int m = 0; m < 4; ++m)
            af[m] = *(const f16x8*)&A_lds[m * 16 + lr][k0 + lk8];
        f16x8 bf[4];
        #pragma unroll
        for (int n = 0; n < 4; ++n)
            bf[n] = *(const f16x8*)(Wt2 + (size_t)(wN0 + n * 16 + lr) * 128 + k0 + lk8);
        #pragma unroll
        for (int m = 0; m < 4; ++m)
            #pragma unroll
            for (int n = 0; n < 4; ++n)
                acc[m][n] = __builtin_amdgcn_mfma_f32_16x16x32_f16(af[m], bf[n], acc[m][n], 0, 0, 0);
    }

    const int dir = wN0 >> 7;
    const int rq  = (l >> 4) * 4;
    #pragma unroll
    for (int n = 0; n < 4; ++n) {
        const int colr = (wN0 + n * 16 + lr) & 127;
        const int colp = (colr & 31) * 4 + (colr >> 5);
        const float bv = dir ? b2b[colr] : b2f[colr];
        #pragma unroll
        for (int m = 0; m < 4; ++m) {
            const size_t rb = (size_t)dir * 32768 + row0 + m * 16 + rq;
            #pragma unroll
            for (int r = 0; r < 4; ++r)
                Z2p[(rb + r) * 128 + colp] = acc[m][n][r] + bv;
        }
    }
}

// ---------------- LSTM layer 1: 2 waves per chain, 2 gate-cols per lane ------
// Block = (b,dir), 128 thr. Lane l of wave w: unit u=w*32+(l>>1), parity p=l&1
// -> gates {p, p+2}. Gate exchange = ONE DPP pair swap. h crosses the 2 waves
// via f16 LDS (double-buffered), lgkm-only barrier. Z: one float4/lane/step
// (permuted colp layout), 4-deep prefetch ring.
__global__ __launch_bounds__(128, 1) void lstm1_kernel(
    const float* __restrict__ Z1p,
    const _Float16* __restrict__ Whr1,
    _Float16* __restrict__ H1f)
{
    const int b   = blockIdx.x & 63;
    const int dir = blockIdx.x >> 6;
    const int tid = threadIdx.x;
    const int w   = tid >> 6;
    const int l   = tid & 63;
    const int p   = l & 1;
    const int u   = w * 32 + (l >> 1);

    // Wh rows colp0 = u*4+p (gate p), colp1 = u*4+p+2 (gate p+2); 64 f16 each.
    h2_t wc0[32], wc1[32];
    {
        const _Float16* __restrict__ wp0 = Whr1 + (size_t)(dir * 256 + u * 4 + p) * 64;
        const _Float16* __restrict__ wp1 = Whr1 + (size_t)(dir * 256 + u * 4 + p + 2) * 64;
        #pragma unroll
        for (int r8 = 0; r8 < 8; ++r8) {
            f16x8 v0 = *(const f16x8*)(wp0 + r8 * 8);
            f16x8 v1 = *(const f16x8*)(wp1 + r8 * 8);
            #pragma unroll
            for (int j = 0; j < 4; ++j) {
                h2_t q0; q0[0] = v0[2 * j]; q0[1] = v0[2 * j + 1]; wc0[r8 * 4 + j] = q0;
                h2_t q1; q1[0] = v1[2 * j]; q1[1] = v1[2 * j + 1]; wc1[r8 * 4 + j] = q1;
            }
        }
    }

    __shared__ __align__(16) _Float16 hbuf[2][64];
    if (tid < 64) { hbuf[0][tid] = (_Float16)0.0f; hbuf[1][tid] = (_Float16)0.0f; }
    lds_barrier();

    float c = 0.0f;

    const float* __restrict__ zrow =
        Z1p + ((size_t)(dir * 64 + b) * T_LEN) * 256 + u * 4;

    float4 zr[4];
    #pragma unroll
    for (int q = 0; q < 4; ++q) {
        int t = dir ? (T_LEN - 1 - q) : q;
        zr[q] = *(const float4*)(zrow + (size_t)t * 256);
    }

    _Float16* __restrict__ hout = H1f + (size_t)b * T_LEN * 128 + dir * 64 + u;

    // act1 (gate p+2): p=0 -> g (tanh), p=1 -> o (sigmoid)
    const float km  = (p == 0) ? -2.0f : -1.0f;
    const float num = (p == 0) ?  2.0f :  1.0f;
    const float off = (p == 0) ?  1.0f :  0.0f;

    for (int sb = 0; sb < T_LEN; sb += 4) {
        #pragma unroll
        for (int q = 0; q < 4; ++q) {
            const int s = sb + q;
            const uint4* hb = (const uint4*)hbuf[s & 1];
            float zc0 = p ? zr[q].y : zr[q].x;     // gate p pre-activation
            float zc1 = p ? zr[q].w : zr[q].z;     // gate p+2 pre-activation

            float a00 = zc0, a01 = 0.f, a10 = zc1, a11 = 0.f;
            #pragma unroll
            for (int k = 0; k < 8; ++k) {
                uint4 hq = hb[k];
                h2_t p0 = __builtin_bit_cast(h2_t, hq.x);
                h2_t p1 = __builtin_bit_cast(h2_t, hq.y);
                h2_t p2 = __builtin_bit_cast(h2_t, hq.z);
                h2_t p3 = __builtin_bit_cast(h2_t, hq.w);
                a00 = FDOT2(p0, wc0[4 * k + 0], a00);
                a01 = FDOT2(p1, wc0[4 * k + 1], a01);
                a00 = FDOT2(p2, wc0[4 * k + 2], a00);
                a01 = FDOT2(p3, wc0[4 * k + 3], a01);
                a10 = FDOT2(p0, wc1[4 * k + 0], a10);
                a11 = FDOT2(p1, wc1[4 * k + 1], a11);
                a10 = FDOT2(p2, wc1[4 * k + 2], a10);
                a11 = FDOT2(p3, wc1[4 * k + 3], a11);
            }
            float z0s = a00 + a01;
            float z1s = a10 + a11;

            {   // refill ring slot (stays in flight across barriers)
                int sp = s + 4; if (sp > T_LEN - 1) sp = T_LEN - 1;
                int tp = dir ? (T_LEN - 1 - sp) : sp;
                zr[q] = *(const float4*)(zrow + (size_t)tp * 256);
            }

            float act0 = sigf(z0s);                 // f (p=0) or i (p=1)
            float e = __expf(km * z1s);
            float act1 = num / (1.0f + e) - off;    // g (p=0) or o (p=1)

            float x0 = dpp_xor1(act0);
            float x1 = dpp_xor1(act1);
            float f_ = p ? x0   : act0;
            float i_ = p ? act0 : x0;
            float g_ = p ? x1   : act1;
            float o_ = p ? act1 : x1;
            c = fmaf(f_, c, i_ * g_);
            float h = o_ * tanhf_(c);
            if (p == 0) {
                int t = dir ? (T_LEN - 1 - s) : s;
                _Float16 h16 = (_Float16)h;
                hout[(size_t)t * 128] = h16;
                hbuf[(s + 1) & 1][u] = h16;
            }
            lds_barrier();
        }
    }
}

// ---------------- LSTM layer 2: ONE wave per b, both dirs, no cross-wave sync --
// Lane l: dir=l>>5, unit u=l&31, ALL 4 gates. h exchange is same-wave LDS
// write -> lgkmcnt -> broadcast read (s_barrier over 1 wave = free).
__global__ __launch_bounds__(64, 1) void lstm2_kernel(
    const float* __restrict__ Z2p,
    const _Float16* __restrict__ Whr2,
    float* __restrict__ H2)
{
    const int b   = blockIdx.x;          // 0..63
    const int l   = threadIdx.x;         // 0..63
    const int dir = l >> 5;
    const int u   = l & 31;

    // 4 gate rows colp = u*4+g of Whr2[dir], 32 f16 each -> 64 h2_t regs.
    h2_t wc[4][16];
    #pragma unroll
    for (int g = 0; g < 4; ++g) {
        const _Float16* __restrict__ wp = Whr2 + (size_t)(dir * 128 + u * 4 + g) * 32;
        #pragma unroll
        for (int r8 = 0; r8 < 4; ++r8) {
            f16x8 v = *(const f16x8*)(wp + r8 * 8);
            #pragma unroll
            for (int j = 0; j < 4; ++j) {
                h2_t q; q[0] = v[2 * j]; q[1] = v[2 * j + 1];
                wc[g][r8 * 4 + j] = q;
            }
        }
    }

    __shared__ __align__(16) _Float16 hbuf[2][32];   // [dir][unit], single-buffered
    hbuf[l >> 5][l & 31] = (_Float16)0.0f;
    lds_barrier();

    float c = 0.0f, h = 0.0f;

    const float* __restrict__ zrow =
        Z2p + ((size_t)(dir * 64 + b) * T_LEN) * 128 + u * 4;

    float4 zr[4];
    #pragma unroll
    for (int q = 0; q < 4; ++q) {
        int t = dir ? (T_LEN - 1 - q) : q;
        zr[q] = *(const float4*)(zrow + (size_t)t * 128);
    }

    const uint4* __restrict__ hb = (const uint4*)hbuf[dir];

    for (int sb = 0; sb < T_LEN; sb += 4) {
        #pragma unroll
        for (int q = 0; q < 4; ++q) {
            const int s = sb + q;
            float a0 = zr[q].x, a1 = zr[q].y, a2 = zr[q].z, a3 = zr[q].w;
            #pragma unroll
            for (int k = 0; k < 4; ++k) {
                uint4 hq = hb[k];
                h2_t p0 = __builtin_bit_cast(h2_t, hq.x);
                h2_t p1 = __builtin_bit_cast(h2_t, hq.y);
                h2_t p2 = __builtin_bit_cast(h2_t, hq.z);
                h2_t p3 = __builtin_bit_cast(h2_t, hq.w);
                a0 = FDOT2(p0, wc[0][4 * k + 0], a0);
                a0 = FDOT2(p1, wc[0][4 * k + 1], a0);
                a0 = FDOT2(p2, wc[0][4 * k + 2], a0);
                a0 = FDOT2(p3, wc[0][4 * k + 3], a0);
                a1 = FDOT2(p0, wc[1][4 * k + 0], a1);
                a1 = FDOT2(p1, wc[1][4 * k + 1], a1);
                a1 = FDOT2(p2, wc[1][4 * k + 2], a1);
                a1 = FDOT2(p3, wc[1][4 * k + 3], a1);
                a2 = FDOT2(p0, wc[2][4 * k + 0], a2);
                a2 = FDOT2(p1, wc[2][4 * k + 1], a2);
                a2 = FDOT2(p2, wc[2][4 * k + 2], a2);
                a2 = FDOT2(p3, wc[2][4 * k + 3], a2);
                a3 = FDOT2(p0, wc[3][4 * k + 0], a3);
                a3 = FDOT2(p1, wc[3][4 * k + 1], a3);
                a3 = FDOT2(p2, wc[3][4 * k + 2], a3);
                a3 = FDOT2(p3, wc[3][4 * k + 3], a3);
            }

            {
                int sp = s + 4; if (sp > T_LEN - 1) sp = T_LEN - 1;
                int tp = dir ? (T_LEN - 1 - sp) : sp;
                zr[q] = *(const float4*)(zrow + (size_t)tp * 128);
            }

            float f = sigf(a0), i = sigf(a1), g = tanhf_(a2), o = sigf(a3);
            c = fmaf(f, c, i * g);
            h = o * tanhf_(c);
            hbuf[dir][u] = (_Float16)h;     // same-wave RAW, fenced below
            lds_barrier();                  // 1 wave: lgkm fence only
        }
    }
    H2[(size_t)b * 64 + dir * 32 + u] = h;
}

// ---------------- Dense head ----------------
__global__ __launch_bounds__(256) void head_kernel(
    const float* __restrict__ H2,
    const float* __restrict__ wd, const float* __restrict__ bd,
    const float* __restrict__ wo, const float* __restrict__ bo,
    float* __restrict__ out)
{
    const int tid = threadIdx.x;
    const int b = tid >> 2, qd = tid & 3;

    float hv[64];
    #pragma unroll
    for (int v = 0; v < 64; ++v) hv[v] = H2[b * 64 + v];

    float part = 0.0f;
    #pragma unroll
    for (int iq = 0; iq < 8; ++iq) {
        int i = qd * 8 + iq;
        float a = bd[i];
        #pragma unroll
        for (int v = 0; v < 64; ++v)
            a = fmaf(hv[v], wd[v * 32 + i], a);
        a = fmaxf(a, 0.0f);
        part = fmaf(a, wo[i], part);
    }

    __shared__ float ps[256];
    ps[tid] = part;
    __syncthreads();
    if (qd == 0) {
        float s = ps[tid] + ps[tid + 1] + ps[tid + 2] + ps[tid + 3];
        out[b] = sigf(s + bo[0]);
    }
}

extern "C" void kernel_launch(void* const* d_in, const int* in_sizes, int n_in,
                              void* d_out, int out_size, void* d_ws, size_t ws_size,
                              hipStream_t stream)
{
    const int*   tok = (const int*)  d_in[0];
    const float* emb = (const float*)d_in[1];
    const float* w1f = (const float*)d_in[2];
    const float* b1f = (const float*)d_in[3];
    const float* w1b = (const float*)d_in[4];
    const float* b1b = (const float*)d_in[5];
    const float* w2f = (const float*)d_in[6];
    const float* b2f = (const float*)d_in[7];
    const float* w2b = (const float*)d_in[8];
    const float* b2b = (const float*)d_in[9];
    const float* wd  = (const float*)d_in[10];
    const float* bd  = (const float*)d_in[11];
    const float* wo  = (const float*)d_in[12];
    const float* bo  = (const float*)d_in[13];
    float* out = (float*)d_out;

    // Workspace:
    //   Z1p: [2*64][512][256] f32 (67.1 MB), colp = u*4+g
    //   H1f: [64][512][128]  f16 (8.4 MB)
    //   H2 : 4096 f32
    //   Wt1: 512*320 f16; Wt2: 256*128 f16; Whr1: 512*64 f16; Whr2: 256*32 f16
    //   Z2p aliases Z1p (dead after lstm1): [2*64][512][128], colp = u*4+g
    float*    Z1p  = (float*)d_ws;
    _Float16* H1f  = (_Float16*)(Z1p + (size_t)16777216);
    float*    H2   = (float*)(H1f + (size_t)4194304);
    _Float16* Wt1  = (_Float16*)(H2 + 4096);
    _Float16* Wt2  = Wt1 + (size_t)512 * 320;
    _Float16* Whr1 = Wt2 + (size_t)256 * 128;
    _Float16* Whr2 = Whr1 + (size_t)512 * 64;
    float*    Z2p  = Z1p;

    prep_w1  <<<512, 64, 0, stream>>>(w1f, w1b, Wt1);
    prep_w2  <<<256, 64, 0, stream>>>(w2f, w2b, Wt2);
    prep_whr1<<<512, 64, 0, stream>>>(w1f, w1b, Whr1);
    prep_whr2<<<256, 64, 0, stream>>>(w2f, w2b, Whr2);
    gemm1_kernel<<<512, 256, 0, stream>>>(tok, emb, Wt1, b1f, b1b, Z1p);
    lstm1_kernel<<<128, 128, 0, stream>>>(Z1p, Whr1, H1f);
    gemm2_kernel<<<512, 256, 0, stream>>>(H1f, Wt2, b2f, b2b, Z2p);
    lstm2_kernel<<<64, 64, 0, stream>>>(Z2p, Whr2, H2);
    head_kernel<<<1, 256, 0, stream>>>(H2, wd, bd, wo, bo, out);
}

// Round 11
// 465.941 us; speedup vs baseline: 1.1406x; 1.1406x over previous
//
#include <hip/hip_runtime.h>

#define T_LEN 512

typedef _Float16 h2_t  __attribute__((ext_vector_type(2)));
typedef _Float16 f16x8 __attribute__((ext_vector_type(8)));
typedef float    f32x4 __attribute__((ext_vector_type(4)));

__device__ __forceinline__ float sigf(float x) {
    return 1.0f / (1.0f + __expf(-x));
}
__device__ __forceinline__ float tanhf_(float x) {
    return 2.0f / (1.0f + __expf(-2.0f * x)) - 1.0f;
}
__device__ __forceinline__ unsigned pack2(float x, float y) {
    h2_t p; p[0] = (_Float16)x; p[1] = (_Float16)y;
    return __builtin_bit_cast(unsigned, p);
}

// DPP quad-perm lane exchanges (VALU speed).
__device__ __forceinline__ float dpp_xor1(float x) {
    int i = __builtin_bit_cast(int, x);
    i = __builtin_amdgcn_mov_dpp(i, 0xB1, 0xF, 0xF, true);   // [1,0,3,2]
    return __builtin_bit_cast(float, i);
}
__device__ __forceinline__ float dpp_xor2(float x) {
    int i = __builtin_bit_cast(int, x);
    i = __builtin_amdgcn_mov_dpp(i, 0x4E, 0xF, 0xF, true);   // [2,3,0,1]
    return __builtin_bit_cast(float, i);
}

#if defined(__has_builtin)
#  if __has_builtin(__builtin_amdgcn_fdot2)
#    define FDOT2(a, b, c) __builtin_amdgcn_fdot2((a), (b), (c), false)
#  endif
#endif
#ifndef FDOT2
__device__ __forceinline__ float fdot2_fb(h2_t a, h2_t b, float c) {
    return fmaf((float)a[0], (float)b[0], fmaf((float)a[1], (float)b[1], c));
}
#  define FDOT2(a, b, c) fdot2_fb((a), (b), (c))
#endif

// Raw barrier: waits LDS ops only (lgkmcnt), leaves global loads in flight.
// For 1-wave workgroups s_barrier is free -> this is just a same-wave LDS fence.
__device__ __forceinline__ void lds_barrier() {
    asm volatile("s_waitcnt lgkmcnt(0)" ::: "memory");
    __builtin_amdgcn_s_barrier();
    asm volatile("" ::: "memory");
}

// ---------------- Prep: Wt1[col 0..511][k 0..319] f16 (x-part, col>=256 -> w1b) --
__global__ __launch_bounds__(64) void prep_w1(
    const float* __restrict__ w1f, const float* __restrict__ w1b,
    _Float16* __restrict__ Wt1)
{
    const int col = blockIdx.x;
    const int t   = threadIdx.x;
    if (t >= 40) return;
    const float* __restrict__ W = (col < 256) ? w1f : w1b;
    const int c = col & 255;
    f16x8 v;
    #pragma unroll
    for (int i = 0; i < 8; ++i) {
        int k = t * 8 + i;
        float x = (k < 300) ? W[(size_t)k * 256 + c] : 0.0f;
        v[i] = (_Float16)x;
    }
    *(f16x8*)(Wt1 + (size_t)col * 320 + t * 8) = v;
}

// ---------------- Prep: Wt2[col 0..255][k 0..127] f16 (x-part, col>=128 -> w2b) --
__global__ __launch_bounds__(64) void prep_w2(
    const float* __restrict__ w2f, const float* __restrict__ w2b,
    _Float16* __restrict__ Wt2)
{
    const int col = blockIdx.x;
    const int t   = threadIdx.x;
    if (t >= 16) return;
    const float* __restrict__ W = (col < 128) ? w2f : w2b;
    const int c = col & 127;
    f16x8 v;
    #pragma unroll
    for (int i = 0; i < 8; ++i) {
        int k = t * 8 + i;
        v[i] = (_Float16)W[(size_t)k * 128 + c];
    }
    *(f16x8*)(Wt2 + (size_t)col * 128 + t * 8) = v;
}

// ---------------- Prep: Whr1[dir*256 + colp][k 0..63] f16, colp = u*4+g ----------
__global__ __launch_bounds__(64) void prep_whr1(
    const float* __restrict__ w1f, const float* __restrict__ w1b,
    _Float16* __restrict__ Whr1)
{
    const int x    = blockIdx.x;          // 0..511
    const int dir  = x >> 8, colp = x & 255;
    const int u = colp >> 2, g = colp & 3;
    const int k = threadIdx.x;            // 0..63
    const float* __restrict__ W = dir ? w1b : w1f;
    Whr1[(size_t)x * 64 + k] = (_Float16)W[(size_t)(300 + k) * 256 + g * 64 + u];
}

// ---------------- Prep: Whr2[dir*128 + colp][k 0..31] f16, colp = u*4+g ----------
__global__ __launch_bounds__(64) void prep_whr2(
    const float* __restrict__ w2f, const float* __restrict__ w2b,
    _Float16* __restrict__ Whr2)
{
    const int x    = blockIdx.x;          // 0..255
    const int dir  = x >> 7, colp = x & 127;
    const int u = colp >> 2, g = colp & 3;
    const int k = threadIdx.x;
    if (k >= 32) return;
    const float* __restrict__ W = dir ? w2b : w2f;
    Whr2[(size_t)x * 32 + k] = (_Float16)W[(size_t)(128 + k) * 128 + g * 32 + u];
}

// ---------------- GEMM1 (MFMA f16): Z1 = gather(emb,tok) @ Wx1 + b1 ----------
// Z1 layout: [dir*64+b][t][256] natural cols (R9-proven, lstm1 reads scalar col).
__global__ __launch_bounds__(256, 1) void gemm1_kernel(
    const int* __restrict__ tok, const float* __restrict__ emb,
    const _Float16* __restrict__ Wt1,
    const float* __restrict__ b1f, const float* __restrict__ b1b,
    float* __restrict__ Z1)
{
    const int row0 = blockIdx.x * 64;            // flat row = b*512 + t
    const int b    = row0 >> 9;
    const int t0   = row0 & 511;
    const int tid  = threadIdx.x;

    __shared__ __align__(16) _Float16 A_lds[64][328];

    {
        const int row = tid >> 2, q = tid & 3;
        const int tk = tok[b * T_LEN + t0 + row];
        const float* __restrict__ src = emb + (size_t)tk * 300 + q * 80;
        #pragma unroll
        for (int i = 0; i < 20; ++i) {
            float4 v;
            if (q == 3 && i >= 15) v = make_float4(0.f, 0.f, 0.f, 0.f);
            else                   v = *(const float4*)(src + i * 4);
            uint2 u; u.x = pack2(v.x, v.y); u.y = pack2(v.z, v.w);
            *(uint2*)&A_lds[row][q * 80 + i * 4] = u;
        }
    }
    __syncthreads();

    const int l   = tid & 63;
    const int w   = tid >> 6;
    const int wN0 = w * 128;
    const int lr  = l & 15;
    const int lk8 = (l >> 4) * 8;

    f32x4 acc[4][8] = {};

    #pragma unroll 2
    for (int ks = 0; ks < 10; ++ks) {
        const int k0 = ks * 32;
        f16x8 af[4];
        #pragma unroll
        for (int m = 0; m < 4; ++m)
            af[m] = *(const f16x8*)&A_lds[m * 16 + lr][k0 + lk8];
        f16x8 bf[8];
        #pragma unroll
        for (int n = 0; n < 8; ++n)
            bf[n] = *(const f16x8*)(Wt1 + (size_t)(wN0 + n * 16 + lr) * 320 + k0 + lk8);
        #pragma unroll
        for (int m = 0; m < 4; ++m)
            #pragma unroll
            for (int n = 0; n < 8; ++n)
                acc[m][n] = __builtin_amdgcn_mfma_f32_16x16x32_f16(af[m], bf[n], acc[m][n], 0, 0, 0);
    }

    const int dir = wN0 >> 8;
    const int rq  = (l >> 4) * 4;
    #pragma unroll
    for (int n = 0; n < 8; ++n) {
        const int colr = (wN0 + n * 16 + lr) & 255;
        const float bv = dir ? b1b[colr] : b1f[colr];
        #pragma unroll
        for (int m = 0; m < 4; ++m) {
            const size_t rb = (size_t)dir * 32768 + row0 + m * 16 + rq;
            #pragma unroll
            for (int r = 0; r < 4; ++r)
                Z1[(rb + r) * 256 + colr] = acc[m][n][r] + bv;
        }
    }
}

// ---------------- GEMM2 (MFMA f16): Z2p = H1f @ Wx2 + b2 ----------------
// H1f: [b][t][128] f16. Z2p: [dir*64+b][t][colp = u*4+g] f32.
__global__ __launch_bounds__(256, 1) void gemm2_kernel(
    const _Float16* __restrict__ H1f,
    const _Float16* __restrict__ Wt2,
    const float* __restrict__ b2f, const float* __restrict__ b2b,
    float* __restrict__ Z2p)
{
    const int row0 = blockIdx.x * 64;
    const int tid  = threadIdx.x;

    __shared__ __align__(16) _Float16 A_lds[64][136];

    {
        const int row = tid >> 2, q = tid & 3;
        const _Float16* __restrict__ src = H1f + (size_t)(row0 + row) * 128 + q * 32;
        #pragma unroll
        for (int i = 0; i < 4; ++i)
            *(f16x8*)&A_lds[row][q * 32 + i * 8] = *(const f16x8*)(src + i * 8);
    }
    __syncthreads();

    const int l   = tid & 63;
    const int w   = tid >> 6;
    const int wN0 = w * 64;
    const int lr  = l & 15;
    const int lk8 = (l >> 4) * 8;

    f32x4 acc[4][4] = {};

    #pragma unroll
    for (int ks = 0; ks < 4; ++ks) {
        const int k0 = ks * 32;
        f16x8 af[4];
        #pragma unroll
        for (int m = 0; m < 4; ++m)
            af[m] = *(const f16x8*)&A_lds[m * 16 + lr][k0 + lk8];
        f16x8 bf[4];
        #pragma unroll
        for (int n = 0; n < 4; ++n)
            bf[n] = *(const f16x8*)(Wt2 + (size_t)(wN0 + n * 16 + lr) * 128 + k0 + lk8);
        #pragma unroll
        for (int m = 0; m < 4; ++m)
            #pragma unroll
            for (int n = 0; n < 4; ++n)
                acc[m][n] = __builtin_amdgcn_mfma_f32_16x16x32_f16(af[m], bf[n], acc[m][n], 0, 0, 0);
    }

    const int dir = wN0 >> 7;
    const int rq  = (l >> 4) * 4;
    #pragma unroll
    for (int n = 0; n < 4; ++n) {
        const int colr = (wN0 + n * 16 + lr) & 127;
        const int colp = (colr & 31) * 4 + (colr >> 5);
        const float bv = dir ? b2b[colr] : b2f[colr];
        #pragma unroll
        for (int m = 0; m < 4; ++m) {
            const size_t rb = (size_t)dir * 32768 + row0 + m * 16 + rq;
            #pragma unroll
            for (int r = 0; r < 4; ++r)
                Z2p[(rb + r) * 128 + colp] = acc[m][n][r] + bv;
        }
    }
}

// ---------------- LSTM layer 1: 4 waves per chain, quad-gate lanes (R9-proven) ---
// Block = (b,dir). Lane l of wave w: unit u=w*16+(l>>2), gate g=l&3, column
// col=g*64+u. 4 gates of a unit in one quad -> 3 DPP quad_perm exchanges.
// Weights wc[32] (32 dwords -> stays in VGPRs; 64 dwords would demote to LDS,
// R10 lesson: 1.1e7 bank conflicts). One lgkm-only barrier per step.
__global__ __launch_bounds__(256, 1) void lstm1_kernel(
    const float* __restrict__ Z1,
    const _Float16* __restrict__ Whr1,
    _Float16* __restrict__ H1f)
{
    const int b   = blockIdx.x & 63;
    const int dir = blockIdx.x >> 6;
    const int tid = threadIdx.x;
    const int w   = tid >> 6;
    const int l   = tid & 63;
    const int g   = l & 3;
    const int u   = w * 16 + (l >> 2);
    const int col = g * 64 + u;

    // Wh column (colp = u*4+g = w*64+l): one contiguous 128B row.
    h2_t wc[32];
    {
        const _Float16* __restrict__ wp = Whr1 + (size_t)(dir * 256 + w * 64 + l) * 64;
        #pragma unroll
        for (int r8 = 0; r8 < 8; ++r8) {
            f16x8 v = *(const f16x8*)(wp + r8 * 8);
            #pragma unroll
            for (int j = 0; j < 4; ++j) {
                h2_t p; p[0] = v[2 * j]; p[1] = v[2 * j + 1];
                wc[r8 * 4 + j] = p;
            }
        }
    }

    __shared__ __align__(16) _Float16 hbuf[2][64];
    if (tid < 64) { hbuf[0][tid] = (_Float16)0.0f; hbuf[1][tid] = (_Float16)0.0f; }
    lds_barrier();

    float c = 0.0f;

    const float* __restrict__ zcol =
        Z1 + ((size_t)(dir * 64 + b) * T_LEN) * 256 + col;

    float zr[4];
    #pragma unroll
    for (int q = 0; q < 4; ++q) {
        int t = dir ? (T_LEN - 1 - q) : q;
        zr[q] = zcol[(size_t)t * 256];
    }

    _Float16* __restrict__ hout = H1f + (size_t)b * T_LEN * 128 + dir * 64 + u;

    const bool s0b = (g & 1) != 0, s1b = (g >> 1) != 0;
    const float km  = (g == 2) ? -2.0f : -1.0f;
    const float num = (g == 2) ?  2.0f :  1.0f;
    const float off = (g == 2) ?  1.0f :  0.0f;

    for (int sb = 0; sb < T_LEN; sb += 4) {
        #pragma unroll
        for (int q = 0; q < 4; ++q) {
            const int s = sb + q;
            const uint4* hb = (const uint4*)hbuf[s & 1];
            float a0 = zr[q], a1 = 0.f, a2 = 0.f, a3 = 0.f;
            #pragma unroll
            for (int k = 0; k < 8; ++k) {
                uint4 hq = hb[k];
                h2_t p0 = __builtin_bit_cast(h2_t, hq.x);
                h2_t p1 = __builtin_bit_cast(h2_t, hq.y);
                h2_t p2 = __builtin_bit_cast(h2_t, hq.z);
                h2_t p3 = __builtin_bit_cast(h2_t, hq.w);
                a0 = FDOT2(p0, wc[4 * k + 0], a0);
                a1 = FDOT2(p1, wc[4 * k + 1], a1);
                a2 = FDOT2(p2, wc[4 * k + 2], a2);
                a3 = FDOT2(p3, wc[4 * k + 3], a3);
            }
            float zz = (a0 + a1) + (a2 + a3);

            {   // refill ring slot (stays in flight across barriers)
                int sp = s + 4; if (sp > T_LEN - 1) sp = T_LEN - 1;
                int tp = dir ? (T_LEN - 1 - sp) : sp;
                zr[q] = zcol[(size_t)tp * 256];
            }

            // own gate activation (sig for f,i,o; tanh for g)
            float e = __expf(km * zz);
            float A = num / (1.0f + e) - off;
            // quad exchange: B=xor1, C=xor2, D=xor3 (all VALU DPP)
            float B = dpp_xor1(A);
            float C = dpp_xor2(A);
            float D = dpp_xor2(B);
            float f_ = s1b ? (s0b ? D : C) : (s0b ? B : A);
            float i_ = s1b ? (s0b ? C : D) : (s0b ? A : B);
            float g_ = s1b ? (s0b ? B : A) : (s0b ? D : C);
            float o_ = s1b ? (s0b ? A : B) : (s0b ? C : D);
            c = fmaf(f_, c, i_ * g_);
            float h = o_ * tanhf_(c);
            _Float16 h16 = (_Float16)h;
            if (g == 0) {
                int t = dir ? (T_LEN - 1 - s) : s;
                hout[(size_t)t * 128] = h16;
                hbuf[(s + 1) & 1][u] = h16;
            }
            lds_barrier();
        }
    }
}

// ---------------- LSTM layer 2: ONE wave per (b,dir), 2 gate-cols per lane ------
// Lane l: unit u=l>>1, parity p=l&1 -> gates {p, p+2}. Weights 32 dwords (safe).
// Gate exchange = one DPP pair swap; h exchange = same-wave LDS write ->
// lgkm fence -> broadcast read. No cross-wave sync (1-wave workgroup).
__global__ __launch_bounds__(64, 1) void lstm2_kernel(
    const float* __restrict__ Z2p,
    const _Float16* __restrict__ Whr2,
    float* __restrict__ H2)
{
    const int b   = blockIdx.x & 63;
    const int dir = blockIdx.x >> 6;
    const int l   = threadIdx.x;         // 0..63
    const int p   = l & 1;
    const int u   = l >> 1;              // 0..31

    // Wh rows colp = u*4+p and u*4+p+2: 32 f16 each -> 16 h2_t each.
    h2_t wc0[16], wc1[16];
    {
        const _Float16* __restrict__ wp0 = Whr2 + (size_t)(dir * 128 + u * 4 + p) * 32;
        const _Float16* __restrict__ wp1 = Whr2 + (size_t)(dir * 128 + u * 4 + p + 2) * 32;
        #pragma unroll
        for (int r8 = 0; r8 < 4; ++r8) {
            f16x8 v0 = *(const f16x8*)(wp0 + r8 * 8);
            f16x8 v1 = *(const f16x8*)(wp1 + r8 * 8);
            #pragma unroll
            for (int j = 0; j < 4; ++j) {
                h2_t q0; q0[0] = v0[2 * j]; q0[1] = v0[2 * j + 1]; wc0[r8 * 4 + j] = q0;
                h2_t q1; q1[0] = v1[2 * j]; q1[1] = v1[2 * j + 1]; wc1[r8 * 4 + j] = q1;
            }
        }
    }

    __shared__ __align__(16) _Float16 hbuf[32];   // single chain, same-wave RAW
    if (p == 0) hbuf[u] = (_Float16)0.0f;
    lds_barrier();

    float c = 0.0f, h = 0.0f;

    const float* __restrict__ zrow =
        Z2p + ((size_t)(dir * 64 + b) * T_LEN) * 128 + u * 4;

    float4 zr[4];
    #pragma unroll
    for (int q = 0; q < 4; ++q) {
        int t = dir ? (T_LEN - 1 - q) : q;
        zr[q] = *(const float4*)(zrow + (size_t)t * 128);
    }

    // act1 (gate p+2): p=0 -> g (tanh), p=1 -> o (sigmoid)
    const float km  = (p == 0) ? -2.0f : -1.0f;
    const float num = (p == 0) ?  2.0f :  1.0f;
    const float off = (p == 0) ?  1.0f :  0.0f;

    const uint4* __restrict__ hb = (const uint4*)hbuf;

    for (int sb = 0; sb < T_LEN; sb += 4) {
        #pragma unroll
        for (int q = 0; q < 4; ++q) {
            const int s = sb + q;
            float zc0 = p ? zr[q].y : zr[q].x;     // gate p pre-activation
            float zc1 = p ? zr[q].w : zr[q].z;     // gate p+2 pre-activation

            float a00 = zc0, a01 = 0.f, a10 = zc1, a11 = 0.f;
            #pragma unroll
            for (int k = 0; k < 2; ++k) {
                uint4 hq = hb[k];
                h2_t p0 = __builtin_bit_cast(h2_t, hq.x);
                h2_t p1 = __builtin_bit_cast(h2_t, hq.y);
                h2_t p2 = __builtin_bit_cast(h2_t, hq.z);
                h2_t p3 = __builtin_bit_cast(h2_t, hq.w);
                a00 = FDOT2(p0, wc0[4 * k + 0], a00);
                a01 = FDOT2(p1, wc0[4 * k + 1], a01);
                a00 = FDOT2(p2, wc0[4 * k + 2], a00);
                a01 = FDOT2(p3, wc0[4 * k + 3], a01);
                a10 = FDOT2(p0, wc1[4 * k + 0], a10);
                a11 = FDOT2(p1, wc1[4 * k + 1], a11);
                a10 = FDOT2(p2, wc1[4 * k + 2], a10);
                a11 = FDOT2(p3, wc1[4 * k + 3], a11);
            }
            float z0s = a00 + a01;
            float z1s = a10 + a11;

            {   // refill ring slot
                int sp = s + 4; if (sp > T_LEN - 1) sp = T_LEN - 1;
                int tp = dir ? (T_LEN - 1 - sp) : sp;
                zr[q] = *(const float4*)(zrow + (size_t)tp * 128);
            }

            float act0 = sigf(z0s);                 // f (p=0) or i (p=1)
            float e = __expf(km * z1s);
            float act1 = num / (1.0f + e) - off;    // g (p=0) or o (p=1)

            float x0 = dpp_xor1(act0);
            float x1 = dpp_xor1(act1);
            float f_ = p ? x0   : act0;
            float i_ = p ? act0 : x0;
            float g_ = p ? x1   : act1;
            float o_ = p ? act1 : x1;
            c = fmaf(f_, c, i_ * g_);
            h = o_ * tanhf_(c);
            if (p == 0) hbuf[u] = (_Float16)h;      // same-wave RAW
            lds_barrier();                          // 1 wave: lgkm fence only
        }
    }
    if (p == 0)
        H2[(size_t)b * 64 + dir * 32 + u] = h;
}

// ---------------- Dense head ----------------
__global__ __launch_bounds__(256) void head_kernel(
    const float* __restrict__ H2,
    const float* __restrict__ wd, const float* __restrict__ bd,
    const float* __restrict__ wo, const float* __restrict__ bo,
    float* __restrict__ out)
{
    const int tid = threadIdx.x;
    const int b = tid >> 2, qd = tid & 3;

    float hv[64];
    #pragma unroll
    for (int v = 0; v < 64; ++v) hv[v] = H2[b * 64 + v];

    float part = 0.0f;
    #pragma unroll
    for (int iq = 0; iq < 8; ++iq) {
        int i = qd * 8 + iq;
        float a = bd[i];
        #pragma unroll
        for (int v = 0; v < 64; ++v)
            a = fmaf(hv[v], wd[v * 32 + i], a);
        a = fmaxf(a, 0.0f);
        part = fmaf(a, wo[i], part);
    }

    __shared__ float ps[256];
    ps[tid] = part;
    __syncthreads();
    if (qd == 0) {
        float s = ps[tid] + ps[tid + 1] + ps[tid + 2] + ps[tid + 3];
        out[b] = sigf(s + bo[0]);
    }
}

extern "C" void kernel_launch(void* const* d_in, const int* in_sizes, int n_in,
                              void* d_out, int out_size, void* d_ws, size_t ws_size,
                              hipStream_t stream)
{
    const int*   tok = (const int*)  d_in[0];
    const float* emb = (const float*)d_in[1];
    const float* w1f = (const float*)d_in[2];
    const float* b1f = (const float*)d_in[3];
    const float* w1b = (const float*)d_in[4];
    const float* b1b = (const float*)d_in[5];
    const float* w2f = (const float*)d_in[6];
    const float* b2f = (const float*)d_in[7];
    const float* w2b = (const float*)d_in[8];
    const float* b2b = (const float*)d_in[9];
    const float* wd  = (const float*)d_in[10];
    const float* bd  = (const float*)d_in[11];
    const float* wo  = (const float*)d_in[12];
    const float* bo  = (const float*)d_in[13];
    float* out = (float*)d_out;

    // Workspace:
    //   Z1 : [2*64][512][256] f32 (67.1 MB), natural cols (lstm1)
    //   H1f: [64][512][128]  f16 (8.4 MB)
    //   H2 : 4096 f32
    //   Wt1: 512*320 f16; Wt2: 256*128 f16; Whr1: 512*64 f16; Whr2: 256*32 f16
    //   Z2p aliases Z1 (dead after lstm1): [2*64][512][128], colp = u*4+g
    float*    Z1   = (float*)d_ws;
    _Float16* H1f  = (_Float16*)(Z1 + (size_t)16777216);
    float*    H2   = (float*)(H1f + (size_t)4194304);
    _Float16* Wt1  = (_Float16*)(H2 + 4096);
    _Float16* Wt2  = Wt1 + (size_t)512 * 320;
    _Float16* Whr1 = Wt2 + (size_t)256 * 128;
    _Float16* Whr2 = Whr1 + (size_t)512 * 64;
    float*    Z2p  = Z1;

    prep_w1  <<<512, 64, 0, stream>>>(w1f, w1b, Wt1);
    prep_w2  <<<256, 64, 0, stream>>>(w2f, w2b, Wt2);
    prep_whr1<<<512, 64, 0, stream>>>(w1f, w1b, Whr1);
    prep_whr2<<<256, 64, 0, stream>>>(w2f, w2b, Whr2);
    gemm1_kernel<<<512, 256, 0, stream>>>(tok, emb, Wt1, b1f, b1b, Z1);
    lstm1_kernel<<<128, 256, 0, stream>>>(Z1, Whr1, H1f);
    gemm2_kernel<<<512, 256, 0, stream>>>(H1f, Wt2, b2f, b2b, Z2p);
    lstm2_kernel<<<128, 64, 0, stream>>>(Z2p, Whr2, H2);
    head_kernel<<<1, 256, 0, stream>>>(H2, wd, bd, wo, bo, out);
}

// Round 12
// 377.572 us; speedup vs baseline: 1.4076x; 1.2340x over previous
//
#include <hip/hip_runtime.h>

#define T_LEN 512

typedef _Float16 h2_t  __attribute__((ext_vector_type(2)));
typedef _Float16 f16x8 __attribute__((ext_vector_type(8)));
typedef float    f32x4 __attribute__((ext_vector_type(4)));

__device__ __forceinline__ float sigf(float x) {
    return 1.0f / (1.0f + __expf(-x));
}
__device__ __forceinline__ float tanhf_(float x) {
    return 2.0f / (1.0f + __expf(-2.0f * x)) - 1.0f;
}
__device__ __forceinline__ unsigned pack2(float x, float y) {
    h2_t p; p[0] = (_Float16)x; p[1] = (_Float16)y;
    return __builtin_bit_cast(unsigned, p);
}
__device__ __forceinline__ h2_t d2u(unsigned x) {
    return __builtin_bit_cast(h2_t, x);
}

// DPP quad-perm lane exchanges (VALU speed).
__device__ __forceinline__ float dpp_xor1(float x) {
    int i = __builtin_bit_cast(int, x);
    i = __builtin_amdgcn_mov_dpp(i, 0xB1, 0xF, 0xF, true);   // [1,0,3,2]
    return __builtin_bit_cast(float, i);
}
__device__ __forceinline__ float dpp_xor2(float x) {
    int i = __builtin_bit_cast(int, x);
    i = __builtin_amdgcn_mov_dpp(i, 0x4E, 0xF, 0xF, true);   // [2,3,0,1]
    return __builtin_bit_cast(float, i);
}

#if defined(__has_builtin)
#  if __has_builtin(__builtin_amdgcn_fdot2)
#    define FDOT2(a, b, c) __builtin_amdgcn_fdot2((a), (b), (c), false)
#  endif
#endif
#ifndef FDOT2
__device__ __forceinline__ float fdot2_fb(h2_t a, h2_t b, float c) {
    return fmaf((float)a[0], (float)b[0], fmaf((float)a[1], (float)b[1], c));
}
#  define FDOT2(a, b, c) fdot2_fb((a), (b), (c))
#endif

// Raw barrier: waits LDS ops only (lgkmcnt), leaves global loads in flight.
// For 1-wave workgroups s_barrier is free -> this is just a same-wave LDS fence.
__device__ __forceinline__ void lds_barrier() {
    asm volatile("s_waitcnt lgkmcnt(0)" ::: "memory");
    __builtin_amdgcn_s_barrier();
    asm volatile("" ::: "memory");
}

// ---------------- Prep: Wt1[col 0..511][k 0..319] f16 (x-part, col>=256 -> w1b) --
__global__ __launch_bounds__(64) void prep_w1(
    const float* __restrict__ w1f, const float* __restrict__ w1b,
    _Float16* __restrict__ Wt1)
{
    const int col = blockIdx.x;
    const int t   = threadIdx.x;
    if (t >= 40) return;
    const float* __restrict__ W = (col < 256) ? w1f : w1b;
    const int c = col & 255;
    f16x8 v;
    #pragma unroll
    for (int i = 0; i < 8; ++i) {
        int k = t * 8 + i;
        float x = (k < 300) ? W[(size_t)k * 256 + c] : 0.0f;
        v[i] = (_Float16)x;
    }
    *(f16x8*)(Wt1 + (size_t)col * 320 + t * 8) = v;
}

// ---------------- Prep: Wt2[col 0..255][k 0..127] f16 (x-part, col>=128 -> w2b) --
__global__ __launch_bounds__(64) void prep_w2(
    const float* __restrict__ w2f, const float* __restrict__ w2b,
    _Float16* __restrict__ Wt2)
{
    const int col = blockIdx.x;
    const int t   = threadIdx.x;
    if (t >= 16) return;
    const float* __restrict__ W = (col < 128) ? w2f : w2b;
    const int c = col & 127;
    f16x8 v;
    #pragma unroll
    for (int i = 0; i < 8; ++i) {
        int k = t * 8 + i;
        v[i] = (_Float16)W[(size_t)k * 128 + c];
    }
    *(f16x8*)(Wt2 + (size_t)col * 128 + t * 8) = v;
}

// ---------------- Prep: Whr1[dir*256 + colp][k 0..63] f16, colp = u*4+g ----------
__global__ __launch_bounds__(64) void prep_whr1(
    const float* __restrict__ w1f, const float* __restrict__ w1b,
    _Float16* __restrict__ Whr1)
{
    const int x    = blockIdx.x;          // 0..511
    const int dir  = x >> 8, colp = x & 255;
    const int u = colp >> 2, g = colp & 3;
    const int k = threadIdx.x;            // 0..63
    const float* __restrict__ W = dir ? w1b : w1f;
    Whr1[(size_t)x * 64 + k] = (_Float16)W[(size_t)(300 + k) * 256 + g * 64 + u];
}

// ---------------- Prep: Whr2[dir*128 + colp][k 0..31] f16, colp = u*4+g ----------
__global__ __launch_bounds__(64) void prep_whr2(
    const float* __restrict__ w2f, const float* __restrict__ w2b,
    _Float16* __restrict__ Whr2)
{
    const int x    = blockIdx.x;          // 0..255
    const int dir  = x >> 7, colp = x & 127;
    const int u = colp >> 2, g = colp & 3;
    const int k = threadIdx.x;
    if (k >= 32) return;
    const float* __restrict__ W = dir ? w2b : w2f;
    Whr2[(size_t)x * 32 + k] = (_Float16)W[(size_t)(128 + k) * 128 + g * 32 + u];
}

// ---------------- GEMM1 (MFMA f16): Z1 = gather(emb,tok) @ Wx1 + b1 ----------
// Z1 layout: [dir*64+b][t][256] natural cols (R9-proven, lstm1 reads scalar col).
__global__ __launch_bounds__(256, 1) void gemm1_kernel(
    const int* __restrict__ tok, const float* __restrict__ emb,
    const _Float16* __restrict__ Wt1,
    const float* __restrict__ b1f, const float* __restrict__ b1b,
    float* __restrict__ Z1)
{
    const int row0 = blockIdx.x * 64;            // flat row = b*512 + t
    const int b    = row0 >> 9;
    const int t0   = row0 & 511;
    const int tid  = threadIdx.x;

    __shared__ __align__(16) _Float16 A_lds[64][328];

    {
        const int row = tid >> 2, q = tid & 3;
        const int tk = tok[b * T_LEN + t0 + row];
        const float* __restrict__ src = emb + (size_t)tk * 300 + q * 80;
        #pragma unroll
        for (int i = 0; i < 20; ++i) {
            float4 v;
            if (q == 3 && i >= 15) v = make_float4(0.f, 0.f, 0.f, 0.f);
            else                   v = *(const float4*)(src + i * 4);
            uint2 u; u.x = pack2(v.x, v.y); u.y = pack2(v.z, v.w);
            *(uint2*)&A_lds[row][q * 80 + i * 4] = u;
        }
    }
    __syncthreads();

    const int l   = tid & 63;
    const int w   = tid >> 6;
    const int wN0 = w * 128;
    const int lr  = l & 15;
    const int lk8 = (l >> 4) * 8;

    f32x4 acc[4][8] = {};

    #pragma unroll 2
    for (int ks = 0; ks < 10; ++ks) {
        const int k0 = ks * 32;
        f16x8 af[4];
        #pragma unroll
        for (int m = 0; m < 4; ++m)
            af[m] = *(const f16x8*)&A_lds[m * 16 + lr][k0 + lk8];
        f16x8 bf[8];
        #pragma unroll
        for (int n = 0; n < 8; ++n)
            bf[n] = *(const f16x8*)(Wt1 + (size_t)(wN0 + n * 16 + lr) * 320 + k0 + lk8);
        #pragma unroll
        for (int m = 0; m < 4; ++m)
            #pragma unroll
            for (int n = 0; n < 8; ++n)
                acc[m][n] = __builtin_amdgcn_mfma_f32_16x16x32_f16(af[m], bf[n], acc[m][n], 0, 0, 0);
    }

    const int dir = wN0 >> 8;
    const int rq  = (l >> 4) * 4;
    #pragma unroll
    for (int n = 0; n < 8; ++n) {
        const int colr = (wN0 + n * 16 + lr) & 255;
        const float bv = dir ? b1b[colr] : b1f[colr];
        #pragma unroll
        for (int m = 0; m < 4; ++m) {
            const size_t rb = (size_t)dir * 32768 + row0 + m * 16 + rq;
            #pragma unroll
            for (int r = 0; r < 4; ++r)
                Z1[(rb + r) * 256 + colr] = acc[m][n][r] + bv;
        }
    }
}

// ---------------- GEMM2 (MFMA f16): Z2p = H1f @ Wx2 + b2 ----------------
// H1f: [b][t][128] f16. Z2p: [dir*64+b][t][colp = u*4+g] f32.
__global__ __launch_bounds__(256, 1) void gemm2_kernel(
    const _Float16* __restrict__ H1f,
    const _Float16* __restrict__ Wt2,
    const float* __restrict__ b2f, const float* __restrict__ b2b,
    float* __restrict__ Z2p)
{
    const int row0 = blockIdx.x * 64;
    const int tid  = threadIdx.x;

    __shared__ __align__(16) _Float16 A_lds[64][136];

    {
        const int row = tid >> 2, q = tid & 3;
        const _Float16* __restrict__ src = H1f + (size_t)(row0 + row) * 128 + q * 32;
        #pragma unroll
        for (int i = 0; i < 4; ++i)
            *(f16x8*)&A_lds[row][q * 32 + i * 8] = *(const f16x8*)(src + i * 8);
    }
    __syncthreads();

    const int l   = tid & 63;
    const int w   = tid >> 6;
    const int wN0 = w * 64;
    const int lr  = l & 15;
    const int lk8 = (l >> 4) * 8;

    f32x4 acc[4][4] = {};

    #pragma unroll
    for (int ks = 0; ks < 4; ++ks) {
        const int k0 = ks * 32;
        f16x8 af[4];
        #pragma unroll
        for (int m = 0; m < 4; ++m)
            af[m] = *(const f16x8*)&A_lds[m * 16 + lr][k0 + lk8];
        f16x8 bf[4];
        #pragma unroll
        for (int n = 0; n < 4; ++n)
            bf[n] = *(const f16x8*)(Wt2 + (size_t)(wN0 + n * 16 + lr) * 128 + k0 + lk8);
        #pragma unroll
        for (int m = 0; m < 4; ++m)
            #pragma unroll
            for (int n = 0; n < 4; ++n)
                acc[m][n] = __builtin_amdgcn_mfma_f32_16x16x32_f16(af[m], bf[n], acc[m][n], 0, 0, 0);
    }

    const int dir = wN0 >> 7;
    const int rq  = (l >> 4) * 4;
    #pragma unroll
    for (int n = 0; n < 4; ++n) {
        const int colr = (wN0 + n * 16 + lr) & 127;
        const int colp = (colr & 31) * 4 + (colr >> 5);
        const float bv = dir ? b2b[colr] : b2f[colr];
        #pragma unroll
        for (int m = 0; m < 4; ++m) {
            const size_t rb = (size_t)dir * 32768 + row0 + m * 16 + rq;
            #pragma unroll
            for (int r = 0; r < 4; ++r)
                Z2p[(rb + r) * 128 + colp] = acc[m][n][r] + bv;
        }
    }
}

// ---------------- LSTM layer 1: 4 waves per chain, quad-gate lanes (R9-proven) ---
// Block = (b,dir). Lane l of wave w: unit u=w*16+(l>>2), gate g=l&3, column
// col=g*64+u. 4 gates of a unit in one quad -> 3 DPP quad_perm exchanges.
// Weights wc[32] (32 dwords, 256-thread block -> stays in VGPRs; R10/R11
// lesson: small-block kernels get private arrays demoted to LDS).
__global__ __launch_bounds__(256, 1) void lstm1_kernel(
    const float* __restrict__ Z1,
    const _Float16* __restrict__ Whr1,
    _Float16* __restrict__ H1f)
{
    const int b   = blockIdx.x & 63;
    const int dir = blockIdx.x >> 6;
    const int tid = threadIdx.x;
    const int w   = tid >> 6;
    const int l   = tid & 63;
    const int g   = l & 3;
    const int u   = w * 16 + (l >> 2);
    const int col = g * 64 + u;

    // Wh column (colp = u*4+g = w*64+l): one contiguous 128B row.
    h2_t wc[32];
    {
        const _Float16* __restrict__ wp = Whr1 + (size_t)(dir * 256 + w * 64 + l) * 64;
        #pragma unroll
        for (int r8 = 0; r8 < 8; ++r8) {
            f16x8 v = *(const f16x8*)(wp + r8 * 8);
            #pragma unroll
            for (int j = 0; j < 4; ++j) {
                h2_t p; p[0] = v[2 * j]; p[1] = v[2 * j + 1];
                wc[r8 * 4 + j] = p;
            }
        }
    }

    __shared__ __align__(16) _Float16 hbuf[2][64];
    if (tid < 64) { hbuf[0][tid] = (_Float16)0.0f; hbuf[1][tid] = (_Float16)0.0f; }
    lds_barrier();

    float c = 0.0f;

    const float* __restrict__ zcol =
        Z1 + ((size_t)(dir * 64 + b) * T_LEN) * 256 + col;

    float zr[4];
    #pragma unroll
    for (int q = 0; q < 4; ++q) {
        int t = dir ? (T_LEN - 1 - q) : q;
        zr[q] = zcol[(size_t)t * 256];
    }

    _Float16* __restrict__ hout = H1f + (size_t)b * T_LEN * 128 + dir * 64 + u;

    const bool s0b = (g & 1) != 0, s1b = (g >> 1) != 0;
    const float km  = (g == 2) ? -2.0f : -1.0f;
    const float num = (g == 2) ?  2.0f :  1.0f;
    const float off = (g == 2) ?  1.0f :  0.0f;

    for (int sb = 0; sb < T_LEN; sb += 4) {
        #pragma unroll
        for (int q = 0; q < 4; ++q) {
            const int s = sb + q;
            const uint4* hb = (const uint4*)hbuf[s & 1];
            float a0 = zr[q], a1 = 0.f, a2 = 0.f, a3 = 0.f;
            #pragma unroll
            for (int k = 0; k < 8; ++k) {
                uint4 hq = hb[k];
                h2_t p0 = __builtin_bit_cast(h2_t, hq.x);
                h2_t p1 = __builtin_bit_cast(h2_t, hq.y);
                h2_t p2 = __builtin_bit_cast(h2_t, hq.z);
                h2_t p3 = __builtin_bit_cast(h2_t, hq.w);
                a0 = FDOT2(p0, wc[4 * k + 0], a0);
                a1 = FDOT2(p1, wc[4 * k + 1], a1);
                a2 = FDOT2(p2, wc[4 * k + 2], a2);
                a3 = FDOT2(p3, wc[4 * k + 3], a3);
            }
            float zz = (a0 + a1) + (a2 + a3);

            {   // refill ring slot (stays in flight across barriers)
                int sp = s + 4; if (sp > T_LEN - 1) sp = T_LEN - 1;
                int tp = dir ? (T_LEN - 1 - sp) : sp;
                zr[q] = zcol[(size_t)tp * 256];
            }

            // own gate activation (sig for f,i,o; tanh for g)
            float e = __expf(km * zz);
            float A = num / (1.0f + e) - off;
            // quad exchange: B=xor1, C=xor2, D=xor3 (all VALU DPP)
            float B = dpp_xor1(A);
            float C = dpp_xor2(A);
            float D = dpp_xor2(B);
            float f_ = s1b ? (s0b ? D : C) : (s0b ? B : A);
            float i_ = s1b ? (s0b ? C : D) : (s0b ? A : B);
            float g_ = s1b ? (s0b ? B : A) : (s0b ? D : C);
            float o_ = s1b ? (s0b ? A : B) : (s0b ? C : D);
            c = fmaf(f_, c, i_ * g_);
            float h = o_ * tanhf_(c);
            _Float16 h16 = (_Float16)h;
            if (g == 0) {
                int t = dir ? (T_LEN - 1 - s) : s;
                hout[(size_t)t * 128] = h16;
                hbuf[(s + 1) & 1][u] = h16;
            }
            lds_barrier();
        }
    }
}

// ---------------- LSTM layer 2: ONE wave per (b,dir), 2 gate-cols per lane ------
// Lane l: unit u=l>>1, parity p=l&1 -> gates {p, p+2}. Weights live in 8 NAMED
// uint4 registers (no allocas -> promote-alloca cannot demote them to LDS; the
// R10/R11 demotions all hit private ARRAYS in small-block kernels). Full K=32
// contraction (R11 bug: only h[0..15] was summed). Gate exchange = one DPP pair
// swap; h exchange = same-wave LDS write -> lgkm fence -> broadcast read.
__global__ __launch_bounds__(64, 1) void lstm2_kernel(
    const float* __restrict__ Z2p,
    const _Float16* __restrict__ Whr2,
    float* __restrict__ H2)
{
    const int b   = blockIdx.x & 63;
    const int dir = blockIdx.x >> 6;
    const int l   = threadIdx.x;         // 0..63
    const int p   = l & 1;
    const int u   = l >> 1;              // 0..31

    // Gate rows colp = u*4+p (gate p) and u*4+p+2 (gate p+2): 32 f16 = 4 uint4 each.
    const uint4* __restrict__ wp0 =
        (const uint4*)(Whr2 + (size_t)(dir * 128 + u * 4 + p) * 32);
    const uint4* __restrict__ wp1 =
        (const uint4*)(Whr2 + (size_t)(dir * 128 + u * 4 + p + 2) * 32);
    const uint4 W00 = wp0[0], W01 = wp0[1], W02 = wp0[2], W03 = wp0[3];
    const uint4 W10 = wp1[0], W11 = wp1[1], W12 = wp1[2], W13 = wp1[3];

    __shared__ __align__(16) _Float16 hbuf[32];   // single chain, same-wave RAW
    if (p == 0) hbuf[u] = (_Float16)0.0f;
    lds_barrier();

    float c = 0.0f, h = 0.0f;

    const float* __restrict__ zrow =
        Z2p + ((size_t)(dir * 64 + b) * T_LEN) * 128 + u * 4;

    float4 zA, zB, zC, zD;                        // named z ring (no alloca)
    { int t = dir ? (T_LEN - 1) : 0; zA = *(const float4*)(zrow + (size_t)t * 128); }
    { int t = dir ? (T_LEN - 2) : 1; zB = *(const float4*)(zrow + (size_t)t * 128); }
    { int t = dir ? (T_LEN - 3) : 2; zC = *(const float4*)(zrow + (size_t)t * 128); }
    { int t = dir ? (T_LEN - 4) : 3; zD = *(const float4*)(zrow + (size_t)t * 128); }

    // act1 (gate p+2): p=0 -> g (tanh), p=1 -> o (sigmoid)
    const float km  = (p == 0) ? -2.0f : -1.0f;
    const float num = (p == 0) ?  2.0f :  1.0f;
    const float off = (p == 0) ?  1.0f :  0.0f;

    const uint4* __restrict__ hb = (const uint4*)hbuf;

// 8 fdot2 over one uint4 h-block (8 h values) for both gate columns.
#define KBLK(HQ, WA, WB)                              \
    a00 = FDOT2(d2u(HQ.x), d2u(WA.x), a00);           \
    a01 = FDOT2(d2u(HQ.y), d2u(WA.y), a01);           \
    a00 = FDOT2(d2u(HQ.z), d2u(WA.z), a00);           \
    a01 = FDOT2(d2u(HQ.w), d2u(WA.w), a01);           \
    a10 = FDOT2(d2u(HQ.x), d2u(WB.x), a10);           \
    a11 = FDOT2(d2u(HQ.y), d2u(WB.y), a11);           \
    a10 = FDOT2(d2u(HQ.z), d2u(WB.z), a10);           \
    a11 = FDOT2(d2u(HQ.w), d2u(WB.w), a11);

#define L2_STEP(ZREG, QOFF)                                               \
    {                                                                     \
        const int s = sb + (QOFF);                                        \
        float zc0 = p ? ZREG.y : ZREG.x;                                  \
        float zc1 = p ? ZREG.w : ZREG.z;                                  \
        uint4 h0 = hb[0], h1 = hb[1], h2q = hb[2], h3 = hb[3];            \
        float a00 = zc0, a01 = 0.f, a10 = zc1, a11 = 0.f;                 \
        KBLK(h0, W00, W10)                                                \
        KBLK(h1, W01, W11)                                                \
        KBLK(h2q, W02, W12)                                               \
        KBLK(h3, W03, W13)                                                \
        float z0s = a00 + a01;                                            \
        float z1s = a10 + a11;                                            \
        {   /* refill ring slot (stays in flight across fences) */        \
            int sp = s + 4; if (sp > T_LEN - 1) sp = T_LEN - 1;           \
            int tp = dir ? (T_LEN - 1 - sp) : sp;                         \
            ZREG = *(const float4*)(zrow + (size_t)tp * 128);             \
        }                                                                 \
        float act0 = sigf(z0s);            /* f (p=0) or i (p=1) */       \
        float e = __expf(km * z1s);                                       \
        float act1 = num / (1.0f + e) - off; /* g (p=0) or o (p=1) */     \
        float x0 = dpp_xor1(act0);                                        \
        float x1 = dpp_xor1(act1);                                        \
        float f_ = p ? x0   : act0;                                       \
        float i_ = p ? act0 : x0;                                         \
        float g_ = p ? x1   : act1;                                       \
        float o_ = p ? act1 : x1;                                         \
        c = fmaf(f_, c, i_ * g_);                                         \
        h = o_ * tanhf_(c);                                               \
        if (p == 0) hbuf[u] = (_Float16)h;   /* same-wave RAW */          \
        lds_barrier();                       /* 1 wave: lgkm fence */     \
    }

    for (int sb = 0; sb < T_LEN; sb += 4) {
        L2_STEP(zA, 0)
        L2_STEP(zB, 1)
        L2_STEP(zC, 2)
        L2_STEP(zD, 3)
    }
#undef L2_STEP
#undef KBLK

    if (p == 0)
        H2[(size_t)b * 64 + dir * 32 + u] = h;
}

// ---------------- Dense head ----------------
__global__ __launch_bounds__(256) void head_kernel(
    const float* __restrict__ H2,
    const float* __restrict__ wd, const float* __restrict__ bd,
    const float* __restrict__ wo, const float* __restrict__ bo,
    float* __restrict__ out)
{
    const int tid = threadIdx.x;
    const int b = tid >> 2, qd = tid & 3;

    float hv[64];
    #pragma unroll
    for (int v = 0; v < 64; ++v) hv[v] = H2[b * 64 + v];

    float part = 0.0f;
    #pragma unroll
    for (int iq = 0; iq < 8; ++iq) {
        int i = qd * 8 + iq;
        float a = bd[i];
        #pragma unroll
        for (int v = 0; v < 64; ++v)
            a = fmaf(hv[v], wd[v * 32 + i], a);
        a = fmaxf(a, 0.0f);
        part = fmaf(a, wo[i], part);
    }

    __shared__ float ps[256];
    ps[tid] = part;
    __syncthreads();
    if (qd == 0) {
        float s = ps[tid] + ps[tid + 1] + ps[tid + 2] + ps[tid + 3];
        out[b] = sigf(s + bo[0]);
    }
}

extern "C" void kernel_launch(void* const* d_in, const int* in_sizes, int n_in,
                              void* d_out, int out_size, void* d_ws, size_t ws_size,
                              hipStream_t stream)
{
    const int*   tok = (const int*)  d_in[0];
    const float* emb = (const float*)d_in[1];
    const float* w1f = (const float*)d_in[2];
    const float* b1f = (const float*)d_in[3];
    const float* w1b = (const float*)d_in[4];
    const float* b1b = (const float*)d_in[5];
    const float* w2f = (const float*)d_in[6];
    const float* b2f = (const float*)d_in[7];
    const float* w2b = (const float*)d_in[8];
    const float* b2b = (const float*)d_in[9];
    const float* wd  = (const float*)d_in[10];
    const float* bd  = (const float*)d_in[11];
    const float* wo  = (const float*)d_in[12];
    const float* bo  = (const float*)d_in[13];
    float* out = (float*)d_out;

    // Workspace:
    //   Z1 : [2*64][512][256] f32 (67.1 MB), natural cols (lstm1)
    //   H1f: [64][512][128]  f16 (8.4 MB)
    //   H2 : 4096 f32
    //   Wt1: 512*320 f16; Wt2: 256*128 f16; Whr1: 512*64 f16; Whr2: 256*32 f16
    //   Z2p aliases Z1 (dead after lstm1): [2*64][512][128], colp = u*4+g
    float*    Z1   = (float*)d_ws;
    _Float16* H1f  = (_Float16*)(Z1 + (size_t)16777216);
    float*    H2   = (float*)(H1f + (size_t)4194304);
    _Float16* Wt1  = (_Float16*)(H2 + 4096);
    _Float16* Wt2  = Wt1 + (size_t)512 * 320;
    _Float16* Whr1 = Wt2 + (size_t)256 * 128;
    _Float16* Whr2 = Whr1 + (size_t)512 * 64;
    float*    Z2p  = Z1;

    prep_w1  <<<512, 64, 0, stream>>>(w1f, w1b, Wt1);
    prep_w2  <<<256, 64, 0, stream>>>(w2f, w2b, Wt2);
    prep_whr1<<<512, 64, 0, stream>>>(w1f, w1b, Whr1);
    prep_whr2<<<256, 64, 0, stream>>>(w2f, w2b, Whr2);
    gemm1_kernel<<<512, 256, 0, stream>>>(tok, emb, Wt1, b1f, b1b, Z1);
    lstm1_kernel<<<128, 256, 0, stream>>>(Z1, Whr1, H1f);
    gemm2_kernel<<<512, 256, 0, stream>>>(H1f, Wt2, b2f, b2b, Z2p);
    lstm2_kernel<<<128, 64, 0, stream>>>(Z2p, Whr2, H2);
    head_kernel<<<1, 256, 0, stream>>>(H2, wd, bd, wo, bo, out);
}